// Round 1
// baseline (1941.562 us; speedup 1.0000x reference)
//
#include <hip/hip_runtime.h>
#include <math.h>

#define B_ 2
#define S_ 2048
#define D_ 512
#define R_ 4

#define BM 64
#define BN 64
#define BK 16

// ---------------------------------------------------------------------------
// C[M,N] = A[M,K] @ B[K,N] (+ bias per column), optional batch via blockIdx.z
// ---------------------------------------------------------------------------
__global__ __launch_bounds__(256) void gemm_nn(const float* __restrict__ A,
                                               const float* __restrict__ Bm,
                                               const float* __restrict__ bias,
                                               float* __restrict__ C,
                                               int M, int N, int K,
                                               long sA, long sB, long sC)
{
    int bz = blockIdx.z;
    A  += (size_t)bz * sA;
    Bm += (size_t)bz * sB;
    C  += (size_t)bz * sC;

    __shared__ float As[BK][BM + 1];
    __shared__ float Bs[BK][BN + 1];

    int row0 = blockIdx.y * BM;
    int col0 = blockIdx.x * BN;
    int tid  = threadIdx.x;
    int tr   = tid >> 4;      // 0..15
    int tc   = tid & 15;      // 0..15

    float acc[4][4] = {};

    for (int k0 = 0; k0 < K; k0 += BK) {
        // A tile: 64 rows x 16 cols, stored transposed As[k][m]
        #pragma unroll
        for (int t = tid; t < BM * BK; t += 256) {
            int r = t >> 4, c = t & 15;
            As[c][r] = A[(size_t)(row0 + r) * K + k0 + c];
        }
        // B tile: 16 rows x 64 cols
        #pragma unroll
        for (int t = tid; t < BK * BN; t += 256) {
            int r = t >> 6, c = t & 63;
            Bs[r][c] = Bm[(size_t)(k0 + r) * N + col0 + c];
        }
        __syncthreads();

        #pragma unroll
        for (int k = 0; k < BK; ++k) {
            float a[4], b[4];
            #pragma unroll
            for (int u = 0; u < 4; ++u) a[u] = As[k][tr * 4 + u];
            #pragma unroll
            for (int v = 0; v < 4; ++v) b[v] = Bs[k][tc * 4 + v];
            #pragma unroll
            for (int u = 0; u < 4; ++u)
                #pragma unroll
                for (int v = 0; v < 4; ++v)
                    acc[u][v] += a[u] * b[v];
        }
        __syncthreads();
    }

    #pragma unroll
    for (int u = 0; u < 4; ++u) {
        int r = row0 + tr * 4 + u;
        #pragma unroll
        for (int v = 0; v < 4; ++v) {
            int c = col0 + tc * 4 + v;
            float bv = bias ? bias[c] : 0.0f;
            C[(size_t)r * N + c] = acc[u][v] + bv;
        }
    }
}

// ---------------------------------------------------------------------------
// scores[b,i,j] = scale * sum_d Q[b,i,d]*K[b,j,d]; skip blocks fully above diag
// ---------------------------------------------------------------------------
__global__ __launch_bounds__(256) void gemm_nt_tri(const float* __restrict__ Q,
                                                   const float* __restrict__ Km,
                                                   float* __restrict__ C,
                                                   float scale)
{
    int b = blockIdx.z;
    const float* A  = Q  + (size_t)b * S_ * D_;
    const float* Bv = Km + (size_t)b * S_ * D_;
    float*       Cb = C  + (size_t)b * S_ * S_;

    int row0 = blockIdx.y * BM;   // i
    int col0 = blockIdx.x * BN;   // j
    if (col0 > row0 + BM - 1) return;   // whole block strictly above diagonal

    __shared__ float As[BK][BM + 1];
    __shared__ float Bs[BK][BN + 1];

    int tid = threadIdx.x;
    int tr  = tid >> 4;
    int tc  = tid & 15;

    float acc[4][4] = {};

    for (int k0 = 0; k0 < D_; k0 += BK) {
        #pragma unroll
        for (int t = tid; t < BM * BK; t += 256) {
            int r = t >> 4, c = t & 15;
            As[c][r] = A[(size_t)(row0 + r) * D_ + k0 + c];
        }
        #pragma unroll
        for (int t = tid; t < BN * BK; t += 256) {
            int r = t >> 4, c = t & 15;
            Bs[c][r] = Bv[(size_t)(col0 + r) * D_ + k0 + c];
        }
        __syncthreads();

        #pragma unroll
        for (int k = 0; k < BK; ++k) {
            float a[4], bb[4];
            #pragma unroll
            for (int u = 0; u < 4; ++u) a[u]  = As[k][tr * 4 + u];
            #pragma unroll
            for (int v = 0; v < 4; ++v) bb[v] = Bs[k][tc * 4 + v];
            #pragma unroll
            for (int u = 0; u < 4; ++u)
                #pragma unroll
                for (int v = 0; v < 4; ++v)
                    acc[u][v] += a[u] * bb[v];
        }
        __syncthreads();
    }

    #pragma unroll
    for (int u = 0; u < 4; ++u) {
        int r = row0 + tr * 4 + u;
        #pragma unroll
        for (int v = 0; v < 4; ++v) {
            int c = col0 + tc * 4 + v;
            Cb[(size_t)r * S_ + c] = acc[u][v] * scale;
        }
    }
}

// ---------------------------------------------------------------------------
// beff[n] = bo[n] + sum_m br_flat[m] * Wo[m,n]
// ---------------------------------------------------------------------------
__global__ __launch_bounds__(512) void beff_kernel(const float* __restrict__ br,
                                                   const float* __restrict__ Wo,
                                                   const float* __restrict__ bo,
                                                   float* __restrict__ beff)
{
    int n = threadIdx.x;
    float acc = bo[n];
    for (int m = 0; m < R_ * D_; ++m)
        acc += br[m] * Wo[(size_t)m * D_ + n];
    beff[n] = acc;
}

// ---------------------------------------------------------------------------
// One block per (b, i): restricted softmax per rate + avg_attention + ctx
// scores and avg_out may alias (read row to LDS first, write at end).
// ---------------------------------------------------------------------------
__global__ __launch_bounds__(256) void softmax_ctx(const float* __restrict__ scores,
                                                   const float* __restrict__ V,
                                                   float* __restrict__ avg_out,
                                                   float* __restrict__ comb)
{
    __shared__ float s_s[S_];
    __shared__ float s_p[S_];
    __shared__ float s_avg[S_];
    __shared__ float red[4];

    int i   = blockIdx.x;
    int b   = blockIdx.y;
    int tid = threadIdx.x;
    int wv  = tid >> 6;
    int ln  = tid & 63;

    const float* srow = scores + ((size_t)b * S_ + i) * S_;

    for (int j = tid; j < S_; j += 256) s_avg[j] = 0.0f;
    for (int j = tid; j <= i; j += 256) s_s[j] = srow[j];
    __syncthreads();

    const int rates[4] = {1, 2, 4, 8};
    const float2* Vb = (const float2*)(V + (size_t)b * S_ * D_);

    for (int ri = 0; ri < 4; ++ri) {
        int rate = rates[ri];
        int cnt  = i / rate + 1;

        // --- max over valid entries ---
        float m = -INFINITY;
        for (int t = tid; t < cnt; t += 256) m = fmaxf(m, s_s[t * rate]);
        #pragma unroll
        for (int o = 32; o > 0; o >>= 1) m = fmaxf(m, __shfl_down(m, o, 64));
        if (ln == 0) red[wv] = m;
        __syncthreads();
        m = fmaxf(fmaxf(red[0], red[1]), fmaxf(red[2], red[3]));
        __syncthreads();

        // --- exp & sum ---
        float sum = 0.0f;
        for (int t = tid; t < cnt; t += 256) {
            float e = __expf(s_s[t * rate] - m);
            s_p[t] = e;
            sum += e;
        }
        #pragma unroll
        for (int o = 32; o > 0; o >>= 1) sum += __shfl_down(sum, o, 64);
        if (ln == 0) red[wv] = sum;
        __syncthreads();
        sum = red[0] + red[1] + red[2] + red[3];
        float inv = 1.0f / sum;

        // --- normalize + accumulate avg attention ---
        for (int t = tid; t < cnt; t += 256) {
            float p = s_p[t] * inv;
            s_p[t] = p;
            s_avg[t * rate] += 0.25f * p;
        }
        __syncthreads();

        // --- ctx_r[d] = sum_t p[t] * V[b, t*rate, d]; thread owns d=2*tid,2*tid+1
        float2 acc = {0.0f, 0.0f};
        for (int t = 0; t < cnt; ++t) {
            float p  = s_p[t];
            float2 v = Vb[(size_t)(t * rate) * (D_ / 2) + tid];
            acc.x += p * v.x;
            acc.y += p * v.y;
        }
        float2* crow = (float2*)(comb + ((size_t)(b * S_ + i) * 4 + ri) * D_);
        crow[tid] = acc;
        __syncthreads();   // s_p / red reused next rate
    }

    float* arow = avg_out + ((size_t)b * S_ + i) * S_;
    for (int j = tid; j < S_; j += 256) arow[j] = s_avg[j];
}

// ---------------------------------------------------------------------------
extern "C" void kernel_launch(void* const* d_in, const int* in_sizes, int n_in,
                              void* d_out, int out_size, void* d_ws, size_t ws_size,
                              hipStream_t stream)
{
    const float* x  = (const float*)d_in[0];
    const float* Wq = (const float*)d_in[1];
    const float* bq = (const float*)d_in[2];
    const float* Wk = (const float*)d_in[3];
    const float* bk = (const float*)d_in[4];
    const float* Wv = (const float*)d_in[5];
    const float* bv = (const float*)d_in[6];
    const float* Wr = (const float*)d_in[7];
    const float* br = (const float*)d_in[8];
    const float* Wo = (const float*)d_in[9];
    const float* bo = (const float*)d_in[10];

    float* out = (float*)d_out;
    float* avg = out + (size_t)B_ * S_ * D_;   // also used as the scores buffer

    float* ws   = (float*)d_ws;
    float* Q    = ws;                          // 2,097,152
    float* Kp   = Q    + (size_t)B_ * S_ * D_; // 2,097,152
    float* V    = Kp   + (size_t)B_ * S_ * D_; // 2,097,152
    float* comb = V    + (size_t)B_ * S_ * D_; // 8,388,608  [B,S,4,D]
    float* Weff = comb + (size_t)B_ * S_ * R_ * D_; // 1,048,576 [4D, D]
    float* beff = Weff + (size_t)R_ * D_ * D_;      // 512

    const int MS = B_ * S_;   // 4096
    const float scale = (float)(1.0 / sqrt((double)D_));

    // effective output weights: Weff[r] = Wr[r] @ Wo[r*D:(r+1)*D, :]
    beff_kernel<<<1, 512, 0, stream>>>(br, Wo, bo, beff);
    gemm_nn<<<dim3(D_ / BN, D_ / BM, R_), 256, 0, stream>>>(
        Wr, Wo, nullptr, Weff, D_, D_, D_,
        (long)D_ * D_, (long)D_ * D_, (long)D_ * D_);

    // Q, K, V projections
    gemm_nn<<<dim3(D_ / BN, MS / BM, 1), 256, 0, stream>>>(
        x, Wq, bq, Q, MS, D_, D_, 0, 0, 0);
    gemm_nn<<<dim3(D_ / BN, MS / BM, 1), 256, 0, stream>>>(
        x, Wk, bk, Kp, MS, D_, D_, 0, 0, 0);
    gemm_nn<<<dim3(D_ / BN, MS / BM, 1), 256, 0, stream>>>(
        x, Wv, bv, V, MS, D_, D_, 0, 0, 0);

    // scores (lower triangle) into the avg_attention region of d_out
    gemm_nt_tri<<<dim3(S_ / BN, S_ / BM, B_), 256, 0, stream>>>(
        Q, Kp, avg, scale);

    // fused restricted softmax + avg attention + ctx per rate
    softmax_ctx<<<dim3(S_, B_), 256, 0, stream>>>(avg, V, avg, comb);

    // output = ctx_flat @ Weff + beff
    gemm_nn<<<dim3(D_ / BN, MS / BM, 1), 256, 0, stream>>>(
        comb, Weff, beff, out, MS, D_, R_ * D_, 0, 0, 0);
}

// Round 2
// 1287.349 us; speedup vs baseline: 1.5082x; 1.5082x over previous
//
#include <hip/hip_runtime.h>
#include <hip/hip_bf16.h>
#include <math.h>

#define B_ 2
#define S_ 2048
#define D_ 512
#define R_ 4
#define KP 3840   // packed P columns: 2048 + 1024 + 512 + 256

#define BM 64
#define BN 64
#define BK 16

// ---------------------------------------------------------------------------
// C[M,N] = A[M,K] @ B[K,N] (+ bias per column), optional batch via blockIdx.z
// ---------------------------------------------------------------------------
__global__ __launch_bounds__(256) void gemm_nn(const float* __restrict__ A,
                                               const float* __restrict__ Bm,
                                               const float* __restrict__ bias,
                                               float* __restrict__ C,
                                               int M, int N, int K,
                                               long sA, long sB, long sC)
{
    int bz = blockIdx.z;
    A  += (size_t)bz * sA;
    Bm += (size_t)bz * sB;
    C  += (size_t)bz * sC;

    __shared__ float As[BK][BM + 1];
    __shared__ float Bs[BK][BN + 1];

    int row0 = blockIdx.y * BM;
    int col0 = blockIdx.x * BN;
    int tid  = threadIdx.x;
    int tr   = tid >> 4;
    int tc   = tid & 15;

    float acc[4][4] = {};

    for (int k0 = 0; k0 < K; k0 += BK) {
        #pragma unroll
        for (int t = tid; t < BM * BK; t += 256) {
            int r = t >> 4, c = t & 15;
            As[c][r] = A[(size_t)(row0 + r) * K + k0 + c];
        }
        #pragma unroll
        for (int t = tid; t < BK * BN; t += 256) {
            int r = t >> 6, c = t & 63;
            Bs[r][c] = Bm[(size_t)(k0 + r) * N + col0 + c];
        }
        __syncthreads();

        #pragma unroll
        for (int k = 0; k < BK; ++k) {
            float a[4], b[4];
            #pragma unroll
            for (int u = 0; u < 4; ++u) a[u] = As[k][tr * 4 + u];
            #pragma unroll
            for (int v = 0; v < 4; ++v) b[v] = Bs[k][tc * 4 + v];
            #pragma unroll
            for (int u = 0; u < 4; ++u)
                #pragma unroll
                for (int v = 0; v < 4; ++v)
                    acc[u][v] += a[u] * b[v];
        }
        __syncthreads();
    }

    #pragma unroll
    for (int u = 0; u < 4; ++u) {
        int r = row0 + tr * 4 + u;
        #pragma unroll
        for (int v = 0; v < 4; ++v) {
            int c = col0 + tc * 4 + v;
            float bv = bias ? bias[c] : 0.0f;
            C[(size_t)r * N + c] = acc[u][v] + bv;
        }
    }
}

// ---------------------------------------------------------------------------
// scores[b,i,j] = scale * sum_d Q[b,i,d]*K[b,j,d]; skip blocks above diagonal
// ---------------------------------------------------------------------------
__global__ __launch_bounds__(256) void gemm_nt_tri(const float* __restrict__ Q,
                                                   const float* __restrict__ Km,
                                                   float* __restrict__ C,
                                                   float scale)
{
    int b = blockIdx.z;
    const float* A  = Q  + (size_t)b * S_ * D_;
    const float* Bv = Km + (size_t)b * S_ * D_;
    float*       Cb = C  + (size_t)b * S_ * S_;

    int row0 = blockIdx.y * BM;
    int col0 = blockIdx.x * BN;
    if (col0 > row0 + BM - 1) return;

    __shared__ float As[BK][BM + 1];
    __shared__ float Bs[BK][BN + 1];

    int tid = threadIdx.x;
    int tr  = tid >> 4;
    int tc  = tid & 15;

    float acc[4][4] = {};

    for (int k0 = 0; k0 < D_; k0 += BK) {
        #pragma unroll
        for (int t = tid; t < BM * BK; t += 256) {
            int r = t >> 4, c = t & 15;
            As[c][r] = A[(size_t)(row0 + r) * D_ + k0 + c];
        }
        #pragma unroll
        for (int t = tid; t < BN * BK; t += 256) {
            int r = t >> 4, c = t & 15;
            Bs[c][r] = Bv[(size_t)(col0 + r) * D_ + k0 + c];
        }
        __syncthreads();

        #pragma unroll
        for (int k = 0; k < BK; ++k) {
            float a[4], bb[4];
            #pragma unroll
            for (int u = 0; u < 4; ++u) a[u]  = As[k][tr * 4 + u];
            #pragma unroll
            for (int v = 0; v < 4; ++v) bb[v] = Bs[k][tc * 4 + v];
            #pragma unroll
            for (int u = 0; u < 4; ++u)
                #pragma unroll
                for (int v = 0; v < 4; ++v)
                    acc[u][v] += a[u] * bb[v];
        }
        __syncthreads();
    }

    #pragma unroll
    for (int u = 0; u < 4; ++u) {
        int r = row0 + tr * 4 + u;
        #pragma unroll
        for (int v = 0; v < 4; ++v) {
            int c = col0 + tc * 4 + v;
            Cb[(size_t)r * S_ + c] = acc[u][v] * scale;
        }
    }
}

// ---------------------------------------------------------------------------
// beff[n] = bo[n] + sum_m br_flat[m] * Wo[m,n]
// ---------------------------------------------------------------------------
__global__ __launch_bounds__(512) void beff_kernel(const float* __restrict__ br,
                                                   const float* __restrict__ Wo,
                                                   const float* __restrict__ bo,
                                                   float* __restrict__ beff)
{
    int n = threadIdx.x;
    float acc = bo[n];
    for (int m = 0; m < R_ * D_; ++m)
        acc += br[m] * Wo[(size_t)m * D_ + n];
    beff[n] = acc;
}

// ---------------------------------------------------------------------------
// W2[b, seg_r + t, n] = sum_d V[b, t*rate, d] * Weff[rIdx*D + d, n]   (bf16)
// Row tiles never straddle segment boundaries (2048/3072/3584 are %64==0).
// ---------------------------------------------------------------------------
__global__ __launch_bounds__(256) void w2_gemm(const float* __restrict__ V,
                                               const float* __restrict__ Weff,
                                               __hip_bfloat16* __restrict__ W2)
{
    int b = blockIdx.z;
    const float* Vb = V + (size_t)b * S_ * D_;

    int row0 = blockIdx.y * BM;   // packed row
    int col0 = blockIdx.x * BN;

    int rate, seg, rIdx;
    if      (row0 >= 3584) { rate = 8; seg = 3584; rIdx = 3; }
    else if (row0 >= 3072) { rate = 4; seg = 3072; rIdx = 2; }
    else if (row0 >= 2048) { rate = 2; seg = 2048; rIdx = 1; }
    else                   { rate = 1; seg = 0;    rIdx = 0; }

    __shared__ float As[BK][BM + 1];
    __shared__ float Bs[BK][BN + 1];

    int tid = threadIdx.x;
    int tr  = tid >> 4;
    int tc  = tid & 15;

    float acc[4][4] = {};

    for (int k0 = 0; k0 < D_; k0 += BK) {
        #pragma unroll
        for (int t = tid; t < BM * BK; t += 256) {
            int r = t >> 4, c = t & 15;
            int vrow = (row0 + r - seg) * rate;
            As[c][r] = Vb[(size_t)vrow * D_ + k0 + c];
        }
        #pragma unroll
        for (int t = tid; t < BK * BN; t += 256) {
            int r = t >> 6, c = t & 63;
            Bs[r][c] = Weff[(size_t)(rIdx * D_ + k0 + r) * D_ + col0 + c];
        }
        __syncthreads();

        #pragma unroll
        for (int k = 0; k < BK; ++k) {
            float a[4], bb[4];
            #pragma unroll
            for (int u = 0; u < 4; ++u) a[u]  = As[k][tr * 4 + u];
            #pragma unroll
            for (int v = 0; v < 4; ++v) bb[v] = Bs[k][tc * 4 + v];
            #pragma unroll
            for (int u = 0; u < 4; ++u)
                #pragma unroll
                for (int v = 0; v < 4; ++v)
                    acc[u][v] += a[u] * bb[v];
        }
        __syncthreads();
    }

    __hip_bfloat16* W2b = W2 + (size_t)b * KP * D_;
    #pragma unroll
    for (int u = 0; u < 4; ++u) {
        int r = row0 + tr * 4 + u;
        #pragma unroll
        for (int v = 0; v < 4; ++v) {
            int c = col0 + tc * 4 + v;
            W2b[(size_t)r * D_ + c] = __float2bfloat16(acc[u][v]);
        }
    }
}

// ---------------------------------------------------------------------------
// One block per (b, i): restricted softmax per rate; write packed bf16 P row
// (zero-padded) + fp32 avg row. scores and avg_out alias (read first).
// ---------------------------------------------------------------------------
__global__ __launch_bounds__(256) void softmax_p(const float* __restrict__ scores,
                                                 float* __restrict__ avg_out,
                                                 __hip_bfloat16* __restrict__ P)
{
    __shared__ float s_s[S_];
    __shared__ float s_p[S_];
    __shared__ float s_avg[S_];
    __shared__ float red[4];

    int i   = blockIdx.x;
    int b   = blockIdx.y;
    int tid = threadIdx.x;
    int wv  = tid >> 6;
    int ln  = tid & 63;

    const float* srow = scores + ((size_t)b * S_ + i) * S_;
    __hip_bfloat16* prow = P + ((size_t)b * S_ + i) * KP;

    for (int j = tid; j < S_; j += 256) s_avg[j] = 0.0f;
    for (int j = tid; j <= i; j += 256) s_s[j] = srow[j];
    __syncthreads();

    const int rates[4]  = {1, 2, 4, 8};
    const int segoff[4] = {0, 2048, 3072, 3584};

    for (int ri = 0; ri < 4; ++ri) {
        int rate   = rates[ri];
        int seg    = segoff[ri];
        int segLen = S_ / rate;
        int cnt    = i / rate + 1;

        float m = -INFINITY;
        for (int t = tid; t < cnt; t += 256) m = fmaxf(m, s_s[t * rate]);
        #pragma unroll
        for (int o = 32; o > 0; o >>= 1) m = fmaxf(m, __shfl_down(m, o, 64));
        if (ln == 0) red[wv] = m;
        __syncthreads();
        m = fmaxf(fmaxf(red[0], red[1]), fmaxf(red[2], red[3]));
        __syncthreads();

        float sum = 0.0f;
        for (int t = tid; t < cnt; t += 256) {
            float e = __expf(s_s[t * rate] - m);
            s_p[t] = e;
            sum += e;
        }
        #pragma unroll
        for (int o = 32; o > 0; o >>= 1) sum += __shfl_down(sum, o, 64);
        if (ln == 0) red[wv] = sum;
        __syncthreads();
        sum = red[0] + red[1] + red[2] + red[3];
        float inv = 1.0f / sum;

        for (int t = tid; t < segLen; t += 256) {
            if (t < cnt) {
                float p = s_p[t] * inv;
                s_avg[t * rate] += 0.25f * p;
                prow[seg + t] = __float2bfloat16(p);
            } else {
                prow[seg + t] = __float2bfloat16(0.0f);
            }
        }
        __syncthreads();
    }

    float* arow = avg_out + ((size_t)b * S_ + i) * S_;
    for (int j = tid; j < S_; j += 256) arow[j] = s_avg[j];
}

// ---------------------------------------------------------------------------
// out[b] = P[b] @ W2[b] + beff, bf16 inputs, fp32 accumulate/output.
// Triangular k-skip: packed col k (segment r) is zero unless (k-seg)*r <= i.
// ---------------------------------------------------------------------------
__global__ __launch_bounds__(256) void gemm_pf(const __hip_bfloat16* __restrict__ P,
                                               const __hip_bfloat16* __restrict__ W2,
                                               const float* __restrict__ beff,
                                               float* __restrict__ out)
{
    int b = blockIdx.z;
    const __hip_bfloat16* A  = P  + (size_t)b * S_ * KP;
    const __hip_bfloat16* Bv = W2 + (size_t)b * KP * D_;
    float*                Cb = out + (size_t)b * S_ * D_;

    int row0 = blockIdx.y * BM;
    int col0 = blockIdx.x * BN;
    int i1   = row0 + BM - 1;   // max row index in tile

    __shared__ float As[BK][BM + 1];
    __shared__ float Bs[BK][BN + 1];

    int tid = threadIdx.x;
    int tr  = tid >> 4;
    int tc  = tid & 15;

    float acc[4][4] = {};

    for (int k0 = 0; k0 < KP; k0 += BK) {
        int rate, seg;
        if      (k0 >= 3584) { rate = 8; seg = 3584; }
        else if (k0 >= 3072) { rate = 4; seg = 3072; }
        else if (k0 >= 2048) { rate = 2; seg = 2048; }
        else                 { rate = 1; seg = 0;    }
        if ((k0 - seg) * rate > i1) continue;   // whole k-block zero for tile

        #pragma unroll
        for (int t = tid; t < BM * BK; t += 256) {
            int r = t >> 4, c = t & 15;
            As[c][r] = __bfloat162float(A[(size_t)(row0 + r) * KP + k0 + c]);
        }
        #pragma unroll
        for (int t = tid; t < BK * BN; t += 256) {
            int r = t >> 6, c = t & 63;
            Bs[r][c] = __bfloat162float(Bv[(size_t)(k0 + r) * D_ + col0 + c]);
        }
        __syncthreads();

        #pragma unroll
        for (int k = 0; k < BK; ++k) {
            float a[4], bb[4];
            #pragma unroll
            for (int u = 0; u < 4; ++u) a[u]  = As[k][tr * 4 + u];
            #pragma unroll
            for (int v = 0; v < 4; ++v) bb[v] = Bs[k][tc * 4 + v];
            #pragma unroll
            for (int u = 0; u < 4; ++u)
                #pragma unroll
                for (int v = 0; v < 4; ++v)
                    acc[u][v] += a[u] * bb[v];
        }
        __syncthreads();
    }

    #pragma unroll
    for (int u = 0; u < 4; ++u) {
        int r = row0 + tr * 4 + u;
        #pragma unroll
        for (int v = 0; v < 4; ++v) {
            int c = col0 + tc * 4 + v;
            Cb[(size_t)r * D_ + c] = acc[u][v] + beff[c];
        }
    }
}

// ---------------------------------------------------------------------------
extern "C" void kernel_launch(void* const* d_in, const int* in_sizes, int n_in,
                              void* d_out, int out_size, void* d_ws, size_t ws_size,
                              hipStream_t stream)
{
    const float* x  = (const float*)d_in[0];
    const float* Wq = (const float*)d_in[1];
    const float* bq = (const float*)d_in[2];
    const float* Wk = (const float*)d_in[3];
    const float* bk = (const float*)d_in[4];
    const float* Wv = (const float*)d_in[5];
    const float* bv = (const float*)d_in[6];
    const float* Wr = (const float*)d_in[7];
    const float* br = (const float*)d_in[8];
    const float* Wo = (const float*)d_in[9];
    const float* bo = (const float*)d_in[10];

    float* out = (float*)d_out;
    float* avg = out + (size_t)B_ * S_ * D_;   // scores buffer, then avg_attention

    const size_t NQ = (size_t)B_ * S_ * D_;    // 2,097,152 floats
    float* ws = (float*)d_ws;
    float* Q  = ws;
    float* Kp = Q + NQ;
    float* V  = Kp + NQ;
    __hip_bfloat16* P = (__hip_bfloat16*)(V + NQ);   // B*S*KP bf16 = 31.5 MB
    // Overlays (written only after Q/K are dead, i.e. after scores GEMM):
    float* Weff = Q;                    // 4*512*512 floats = 4 MB  (< 8.39 MB)
    float* beff = Q + (size_t)R_ * D_ * D_;          // 512 floats
    __hip_bfloat16* W2 = (__hip_bfloat16*)Kp;        // B*KP*D bf16 = 7.86 MB

    const int MS = B_ * S_;
    const float scale = (float)(1.0 / sqrt((double)D_));

    // Q, K, V projections
    gemm_nn<<<dim3(D_ / BN, MS / BM, 1), 256, 0, stream>>>(
        x, Wq, bq, Q, MS, D_, D_, 0, 0, 0);
    gemm_nn<<<dim3(D_ / BN, MS / BM, 1), 256, 0, stream>>>(
        x, Wk, bk, Kp, MS, D_, D_, 0, 0, 0);
    gemm_nn<<<dim3(D_ / BN, MS / BM, 1), 256, 0, stream>>>(
        x, Wv, bv, V, MS, D_, D_, 0, 0, 0);

    // scores (lower triangle) into the avg_attention region of d_out
    gemm_nt_tri<<<dim3(S_ / BN, S_ / BM, B_), 256, 0, stream>>>(
        Q, Kp, avg, scale);

    // ---- Q, K now dead: build Weff/beff/W2 into their space ----
    gemm_nn<<<dim3(D_ / BN, D_ / BM, R_), 256, 0, stream>>>(
        Wr, Wo, nullptr, Weff, D_, D_, D_,
        (long)D_ * D_, (long)D_ * D_, (long)D_ * D_);
    beff_kernel<<<1, 512, 0, stream>>>(br, Wo, bo, beff);
    w2_gemm<<<dim3(D_ / BN, KP / BM, B_), 256, 0, stream>>>(V, Weff, W2);

    // restricted softmax per rate -> packed bf16 P + fp32 avg
    softmax_p<<<dim3(S_, B_), 256, 0, stream>>>(avg, avg, P);

    // out = P @ W2 + beff  (per batch, triangular k-skip)
    gemm_pf<<<dim3(D_ / BN, S_ / BM, B_), 256, 0, stream>>>(P, W2, beff, out);
}

// Round 3
// 331.002 us; speedup vs baseline: 5.8657x; 3.8892x over previous
//
#include <hip/hip_runtime.h>
#include <hip/hip_bf16.h>
#include <math.h>

#define B_ 2
#define S_ 2048
#define D_ 512
#define R_ 4
#define KP 3840   // packed P columns: 2048 + 1024 + 512 + 256

typedef __attribute__((ext_vector_type(8))) __bf16 bf16x8;
typedef __attribute__((ext_vector_type(4))) float f32x4;

enum { M_QKV = 0, M_SCORES = 1, M_WEFFT = 2, M_W2T = 3, M_PF = 4 };

// async global -> LDS, 16 B per lane. lds ptr must be wave-uniform base.
__device__ __forceinline__ void g2l16(const void* gp, void* lp) {
    __builtin_amdgcn_global_load_lds(
        (const __attribute__((address_space(1))) unsigned int*)(unsigned long long)gp,
        (__attribute__((address_space(3))) unsigned int*)(unsigned int)(unsigned long long)lp,
        16, 0, 0);
}

// ---------------------------------------------------------------------------
// Generic NT MFMA GEMM: C[m,n] = sum_k A[m,k] * B[n,k]  (bf16 in, fp32 acc)
// 4 waves in 2x2 arrangement; BK=64; global_load_lds staging; 16x16x32 MFMA.
// ---------------------------------------------------------------------------
template<int MODE, int TBM, int TBN>
__global__ __launch_bounds__(256) void mfma_nt(
    const short* __restrict__ A, const short* __restrict__ B,
    const float* __restrict__ bias, void* __restrict__ Cv,
    int lda, int ldb, int ldc, int K,
    long strA, long strB, long strC, float scale)
{
    constexpr int WM = TBM / 2, WN = TBN / 2;
    constexpr int FM = WM / 16, FN = WN / 16;

    __shared__ __bf16 sAt[TBM * 64];
    __shared__ __bf16 sBt[TBN * 64];

    const int tid  = threadIdx.x;
    const int lane = tid & 63, wid = tid >> 6;
    const int ln15 = lane & 15, quad = lane >> 4;
    const int wy = wid & 1, wx = wid >> 1;

    const int col0 = blockIdx.x * TBN;
    const int row0 = blockIdx.y * TBM;
    const int z    = blockIdx.z;

    if constexpr (MODE == M_SCORES) {
        if (col0 > row0 + TBM - 1) return;   // block strictly above diagonal
    }

    const short* Ab = A + (size_t)z * strA;
    const short* Bb = B + (size_t)z * strB;

    int rate = 1, seg = 0;
    if constexpr (MODE == M_W2T) {
        int rIdx;
        if      (col0 >= 3584) { rate = 8; seg = 3584; rIdx = 3; }
        else if (col0 >= 3072) { rate = 4; seg = 3072; rIdx = 2; }
        else if (col0 >= 2048) { rate = 2; seg = 2048; rIdx = 1; }
        else                   { rate = 1; seg = 0;    rIdx = 0; }
        Ab += (size_t)rIdx * D_ * D_;        // WeffT for this rate
    }

    f32x4 acc[FM][FN];
    #pragma unroll
    for (int u = 0; u < FM; ++u)
        #pragma unroll
        for (int v = 0; v < FN; ++v)
            acc[u][v] = (f32x4){0.f, 0.f, 0.f, 0.f};

    for (int k0 = 0; k0 < K; k0 += 64) {
        if constexpr (MODE == M_PF) {
            int kr, ks;
            if      (k0 >= 3584) { kr = 8; ks = 3584; }
            else if (k0 >= 3072) { kr = 4; ks = 3072; }
            else if (k0 >= 2048) { kr = 2; ks = 2048; }
            else                 { kr = 1; ks = 0;    }
            if ((k0 - ks) * kr > row0 + TBM - 1) continue;  // zero k-block
        }

        // stage A tile: TBM rows x 64 cols bf16 (8 chunks of 16B per row)
        #pragma unroll
        for (int t = 0; t < TBM * 8; t += 256) {
            int idx = t + tid;
            int r = idx >> 3, c = idx & 7;
            const short* g = Ab + (size_t)(row0 + r) * lda + k0 + c * 8;
            g2l16(g, (char*)sAt + (t + wid * 64) * 16);
        }
        // stage B tile: TBN rows x 64 cols
        #pragma unroll
        for (int t = 0; t < TBN * 8; t += 256) {
            int idx = t + tid;
            int r = idx >> 3, c = idx & 7;
            int grow;
            if constexpr (MODE == M_W2T) grow = (col0 + r - seg) * rate;
            else                         grow = col0 + r;
            const short* g = Bb + (size_t)grow * ldb + k0 + c * 8;
            g2l16(g, (char*)sBt + (t + wid * 64) * 16);
        }
        __syncthreads();

        #pragma unroll
        for (int kk = 0; kk < 64; kk += 32) {
            bf16x8 af[FM], bfr[FN];
            #pragma unroll
            for (int u = 0; u < FM; ++u)
                af[u] = *(const bf16x8*)&sAt[(wy * WM + u * 16 + ln15) * 64 + kk + quad * 8];
            #pragma unroll
            for (int v = 0; v < FN; ++v)
                bfr[v] = *(const bf16x8*)&sBt[(wx * WN + v * 16 + ln15) * 64 + kk + quad * 8];
            #pragma unroll
            for (int u = 0; u < FM; ++u)
                #pragma unroll
                for (int v = 0; v < FN; ++v)
                    acc[u][v] = __builtin_amdgcn_mfma_f32_16x16x32_bf16(
                        af[u], bfr[v], acc[u][v], 0, 0, 0);
        }
        __syncthreads();
    }

    // epilogue: C/D layout col=lane&15, row=quad*4+reg
    constexpr bool OUTBF = (MODE == M_QKV || MODE == M_WEFFT || MODE == M_W2T);
    #pragma unroll
    for (int u = 0; u < FM; ++u) {
        int rg = row0 + wy * WM + u * 16 + quad * 4;
        #pragma unroll
        for (int v = 0; v < FN; ++v) {
            int cg = col0 + wx * WN + v * 16 + ln15;
            float bv = 0.f;
            if constexpr (MODE == M_QKV || MODE == M_PF) bv = bias[cg];
            #pragma unroll
            for (int rr = 0; rr < 4; ++rr) {
                float val = acc[u][v][rr];
                if constexpr (MODE == M_SCORES) val *= scale;
                val += bv;
                if constexpr (OUTBF)
                    ((__hip_bfloat16*)Cv)[(size_t)z * strC + (size_t)(rg + rr) * ldc + cg] =
                        __float2bfloat16(val);
                else
                    ((float*)Cv)[(size_t)z * strC + (size_t)(rg + rr) * ldc + cg] = val;
            }
        }
    }
}

// ---------------------------------------------------------------------------
__global__ __launch_bounds__(256) void cvt_bf16(const float* __restrict__ in,
                                                __hip_bfloat16* __restrict__ out, int n)
{
    int i = (blockIdx.x * 256 + threadIdx.x) * 4;
    if (i >= n) return;
    float4 v = *(const float4*)(in + i);
    out[i + 0] = __float2bfloat16(v.x);
    out[i + 1] = __float2bfloat16(v.y);
    out[i + 2] = __float2bfloat16(v.z);
    out[i + 3] = __float2bfloat16(v.w);
}

// out[c][r] (bf16) = in[r][c] (fp32); in is [Rr][Cc]
__global__ __launch_bounds__(256) void transpose_cvt(const float* __restrict__ in,
                                                     __hip_bfloat16* __restrict__ out,
                                                     int Rr, int Cc)
{
    __shared__ float t[32][33];
    int c0 = blockIdx.x * 32, r0 = blockIdx.y * 32;
    int tx = threadIdx.x & 31, ty = threadIdx.x >> 5;   // ty: 0..7
    #pragma unroll
    for (int dy = 0; dy < 32; dy += 8)
        t[ty + dy][tx] = in[(size_t)(r0 + ty + dy) * Cc + c0 + tx];
    __syncthreads();
    #pragma unroll
    for (int dy = 0; dy < 32; dy += 8)
        out[(size_t)(c0 + ty + dy) * Rr + r0 + tx] = __float2bfloat16(t[tx][ty + dy]);
}

// beff[n] = bo[n] + sum_m br_flat[m] * Wo[m,n]
__global__ __launch_bounds__(512) void beff_kernel(const float* __restrict__ br,
                                                   const float* __restrict__ Wo,
                                                   const float* __restrict__ bo,
                                                   float* __restrict__ beff)
{
    int n = threadIdx.x;
    float acc = bo[n];
    for (int m = 0; m < R_ * D_; ++m)
        acc += br[m] * Wo[(size_t)m * D_ + n];
    beff[n] = acc;
}

// ---------------------------------------------------------------------------
// One block per (b, i): restricted softmax per rate; write packed bf16 P row
// (zero-padded) + fp32 avg row. scores and avg_out alias (read first).
// ---------------------------------------------------------------------------
__global__ __launch_bounds__(256) void softmax_p(const float* __restrict__ scores,
                                                 float* __restrict__ avg_out,
                                                 __hip_bfloat16* __restrict__ P)
{
    __shared__ float s_s[S_];
    __shared__ float s_p[S_];
    __shared__ float s_avg[S_];
    __shared__ float red[4];

    int i   = blockIdx.x;
    int b   = blockIdx.y;
    int tid = threadIdx.x;
    int wv  = tid >> 6;
    int ln  = tid & 63;

    const float* srow = scores + ((size_t)b * S_ + i) * S_;
    __hip_bfloat16* prow = P + ((size_t)b * S_ + i) * KP;

    for (int j = tid; j < S_; j += 256) s_avg[j] = 0.0f;
    for (int j = tid; j <= i; j += 256) s_s[j] = srow[j];
    __syncthreads();

    const int rates[4]  = {1, 2, 4, 8};
    const int segoff[4] = {0, 2048, 3072, 3584};

    for (int ri = 0; ri < 4; ++ri) {
        int rate   = rates[ri];
        int seg    = segoff[ri];
        int segLen = S_ / rate;
        int cnt    = i / rate + 1;

        float m = -INFINITY;
        for (int t = tid; t < cnt; t += 256) m = fmaxf(m, s_s[t * rate]);
        #pragma unroll
        for (int o = 32; o > 0; o >>= 1) m = fmaxf(m, __shfl_down(m, o, 64));
        if (ln == 0) red[wv] = m;
        __syncthreads();
        m = fmaxf(fmaxf(red[0], red[1]), fmaxf(red[2], red[3]));
        __syncthreads();

        float sum = 0.0f;
        for (int t = tid; t < cnt; t += 256) {
            float e = __expf(s_s[t * rate] - m);
            s_p[t] = e;
            sum += e;
        }
        #pragma unroll
        for (int o = 32; o > 0; o >>= 1) sum += __shfl_down(sum, o, 64);
        if (ln == 0) red[wv] = sum;
        __syncthreads();
        sum = red[0] + red[1] + red[2] + red[3];
        float inv = 1.0f / sum;

        for (int t = tid; t < segLen; t += 256) {
            if (t < cnt) {
                float p = s_p[t] * inv;
                s_avg[t * rate] += 0.25f * p;
                prow[seg + t] = __float2bfloat16(p);
            } else {
                prow[seg + t] = __float2bfloat16(0.0f);
            }
        }
        __syncthreads();
    }

    float* arow = avg_out + ((size_t)b * S_ + i) * S_;
    for (int j = tid; j < S_; j += 256) arow[j] = s_avg[j];
}

// ---------------------------------------------------------------------------
extern "C" void kernel_launch(void* const* d_in, const int* in_sizes, int n_in,
                              void* d_out, int out_size, void* d_ws, size_t ws_size,
                              hipStream_t stream)
{
    const float* x  = (const float*)d_in[0];
    const float* Wq = (const float*)d_in[1];
    const float* bq = (const float*)d_in[2];
    const float* Wk = (const float*)d_in[3];
    const float* bk = (const float*)d_in[4];
    const float* Wv = (const float*)d_in[5];
    const float* bv = (const float*)d_in[6];
    const float* Wr = (const float*)d_in[7];
    const float* br = (const float*)d_in[8];
    const float* Wo = (const float*)d_in[9];
    const float* bo = (const float*)d_in[10];

    float* out    = (float*)d_out;
    float* scores = out + (size_t)B_ * S_ * D_;  // avg_attention region doubles as scores

    // ---- workspace layout (bytes) ----
    char* wsb = (char*)d_ws;
    short* xb  = (short*)(wsb);                         //  4 MB  bf16 x
    short* Qb  = (short*)(wsb + (4u << 20));            //  4 MB
    short* Kb  = (short*)(wsb + (8u << 20));            //  4 MB
    short* Vb  = (short*)(wsb + (12u << 20));           //  4 MB
    short* P   = (short*)(wsb + (16u << 20));           // 31.5 MB (written by softmax_p)
    short* W2T = (short*)(wsb + (16u << 20) + 31457280u); // 7.86 MB
    float* beff = (float*)(wsb + (16u << 20) + 31457280u + 7864320u); // 2 KB
    // small weight buffers live INSIDE the P region (all dead before softmax_p):
    short* WqT   = P;                                   // 512 KB
    short* WkT   = (short*)((char*)P + 524288);
    short* WvT   = (short*)((char*)P + 1048576);
    short* Wrb   = (short*)((char*)P + 1572864);        // 2 MB
    short* WoT   = (short*)((char*)P + 3670016);        // 2 MB
    short* WeffT = (short*)((char*)P + 5767168);        // 2 MB

    const float scale = (float)(1.0 / sqrt((double)D_));

    // ---- conversions / transposes ----
    cvt_bf16<<<dim3(2048), 256, 0, stream>>>(x,  (__hip_bfloat16*)xb,  B_ * S_ * D_);
    cvt_bf16<<<dim3(1024), 256, 0, stream>>>(Wr, (__hip_bfloat16*)Wrb, R_ * D_ * D_);
    transpose_cvt<<<dim3(16, 16), 256, 0, stream>>>(Wq, (__hip_bfloat16*)WqT, 512, 512);
    transpose_cvt<<<dim3(16, 16), 256, 0, stream>>>(Wk, (__hip_bfloat16*)WkT, 512, 512);
    transpose_cvt<<<dim3(16, 16), 256, 0, stream>>>(Wv, (__hip_bfloat16*)WvT, 512, 512);
    transpose_cvt<<<dim3(16, 64), 256, 0, stream>>>(Wo, (__hip_bfloat16*)WoT, 2048, 512);
    beff_kernel<<<1, 512, 0, stream>>>(br, Wo, bo, beff);

    // ---- Q, K, V projections (bf16 out): C[m,n] = x[m,:] . WT[n,:] + b[n] ----
    mfma_nt<M_QKV, 64, 128><<<dim3(4, 64, 1), 256, 0, stream>>>(
        xb, WqT, bq, Qb, 512, 512, 512, 512, 0, 0, 0, 0.f);
    mfma_nt<M_QKV, 64, 128><<<dim3(4, 64, 1), 256, 0, stream>>>(
        xb, WkT, bk, Kb, 512, 512, 512, 512, 0, 0, 0, 0.f);
    mfma_nt<M_QKV, 64, 128><<<dim3(4, 64, 1), 256, 0, stream>>>(
        xb, WvT, bv, Vb, 512, 512, 512, 512, 0, 0, 0, 0.f);

    // ---- scores = Q K^T * scale (lower-triangle blocks only), fp32 ----
    mfma_nt<M_SCORES, 128, 128><<<dim3(16, 16, 2), 256, 0, stream>>>(
        Qb, Kb, nullptr, scores, 512, 512, 2048, 512,
        (long)S_ * D_, (long)S_ * D_, (long)S_ * S_, scale);

    // ---- WeffT[r][n][d] = sum_m WoT[n][r*512+m] * Wr[r][d][m] (bf16) ----
    mfma_nt<M_WEFFT, 128, 128><<<dim3(4, 4, 4), 256, 0, stream>>>(
        WoT, Wrb, nullptr, WeffT, 2048, 512, 512, 512,
        512, (long)D_ * D_, (long)D_ * D_, 0.f);

    // ---- W2T[b][n][packed j] = sum_d WeffT_r[n][d] * V[b][(j-seg)*rate][d] ----
    mfma_nt<M_W2T, 128, 128><<<dim3(30, 4, 2), 256, 0, stream>>>(
        WeffT, Vb, nullptr, W2T, 512, 512, 3840, 512,
        0, (long)S_ * D_, (long)512 * KP, 0.f);

    // ---- restricted softmax -> packed bf16 P + fp32 avg (overwrites scores) ----
    softmax_p<<<dim3(S_, B_), 256, 0, stream>>>(scores, scores, (__hip_bfloat16*)P);

    // ---- out[b] = P[b] @ W2[b] + beff (k-skip on zero segments), fp32 ----
    mfma_nt<M_PF, 64, 128><<<dim3(4, 32, 2), 256, 0, stream>>>(
        P, W2T, beff, out, 3840, 3840, 512, 3840,
        (long)S_ * KP, (long)512 * KP, (long)S_ * D_, 0.f);
}

// Round 4
// 242.244 us; speedup vs baseline: 8.0149x; 1.3664x over previous
//
#include <hip/hip_runtime.h>
#include <hip/hip_bf16.h>
#include <math.h>

#define B_ 2
#define S_ 2048
#define D_ 512
#define R_ 4
#define KP 3840   // packed P columns: 2048 + 1024 + 512 + 256

typedef __attribute__((ext_vector_type(8))) __bf16 bf16x8;
typedef __attribute__((ext_vector_type(4))) float f32x4;

enum { M_QKV = 0, M_SCORES = 1, M_WEFFT = 2, M_W2T = 3, M_PF = 4 };

// async global -> LDS, 16 B per lane. lds ptr must be wave-uniform base.
__device__ __forceinline__ void g2l16(const void* gp, void* lp) {
    __builtin_amdgcn_global_load_lds(
        (const __attribute__((address_space(1))) unsigned int*)(unsigned long long)gp,
        (__attribute__((address_space(3))) unsigned int*)(unsigned int)(unsigned long long)lp,
        16, 0, 0);
}

// ---------------------------------------------------------------------------
// Generic NT MFMA GEMM: C[m,n] = sum_k A[m,k] * B[n,k]  (bf16 in, fp32 acc)
// 4 waves in 2x2 arrangement; BK=64; global_load_lds staging; 16x16x32 MFMA.
// ---------------------------------------------------------------------------
template<int MODE, int TBM, int TBN>
__global__ __launch_bounds__(256) void mfma_nt(
    const short* __restrict__ A, const short* __restrict__ B,
    const float* __restrict__ bias, void* __restrict__ Cv,
    int lda, int ldb, int ldc, int K,
    long strA, long strB, long strC, long strBias, float scale)
{
    constexpr int WM = TBM / 2, WN = TBN / 2;
    constexpr int FM = WM / 16, FN = WN / 16;

    __shared__ __bf16 sAt[TBM * 64];
    __shared__ __bf16 sBt[TBN * 64];

    const int tid  = threadIdx.x;
    const int lane = tid & 63, wid = tid >> 6;
    const int ln15 = lane & 15, quad = lane >> 4;
    const int wy = wid & 1, wx = wid >> 1;

    // heavy-first row order for PF (k-skip load imbalance)
    const int by   = (MODE == M_PF) ? (gridDim.y - 1 - blockIdx.y) : blockIdx.y;
    const int col0 = blockIdx.x * TBN;
    const int row0 = by * TBM;
    const int z    = blockIdx.z;

    if constexpr (MODE == M_SCORES) {
        if (col0 > row0 + TBM - 1) return;   // block strictly above diagonal
    }

    const short* Ab = A + (size_t)z * strA;
    const short* Bb = B + (size_t)z * strB;
    const float* biasb = bias + (size_t)z * strBias;

    int rate = 1, seg = 0;
    if constexpr (MODE == M_W2T) {
        int rIdx;
        if      (col0 >= 3584) { rate = 8; seg = 3584; rIdx = 3; }
        else if (col0 >= 3072) { rate = 4; seg = 3072; rIdx = 2; }
        else if (col0 >= 2048) { rate = 2; seg = 2048; rIdx = 1; }
        else                   { rate = 1; seg = 0;    rIdx = 0; }
        Ab += (size_t)rIdx * D_ * D_;        // WeffT for this rate
    }

    f32x4 acc[FM][FN];
    #pragma unroll
    for (int u = 0; u < FM; ++u)
        #pragma unroll
        for (int v = 0; v < FN; ++v)
            acc[u][v] = (f32x4){0.f, 0.f, 0.f, 0.f};

    for (int k0 = 0; k0 < K; k0 += 64) {
        if constexpr (MODE == M_PF) {
            int kr, ks;
            if      (k0 >= 3584) { kr = 8; ks = 3584; }
            else if (k0 >= 3072) { kr = 4; ks = 3072; }
            else if (k0 >= 2048) { kr = 2; ks = 2048; }
            else                 { kr = 1; ks = 0;    }
            if ((k0 - ks) * kr > row0 + TBM - 1) continue;  // zero k-block
        }

        // stage A tile: TBM rows x 64 cols bf16 (8 chunks of 16B per row)
        #pragma unroll
        for (int t = 0; t < TBM * 8; t += 256) {
            int idx = t + tid;
            int r = idx >> 3, c = idx & 7;
            const short* g = Ab + (size_t)(row0 + r) * lda + k0 + c * 8;
            g2l16(g, (char*)sAt + (t + wid * 64) * 16);
        }
        // stage B tile: TBN rows x 64 cols
        #pragma unroll
        for (int t = 0; t < TBN * 8; t += 256) {
            int idx = t + tid;
            int r = idx >> 3, c = idx & 7;
            int grow;
            if constexpr (MODE == M_W2T) grow = (col0 + r - seg) * rate;
            else                         grow = col0 + r;
            const short* g = Bb + (size_t)grow * ldb + k0 + c * 8;
            g2l16(g, (char*)sBt + (t + wid * 64) * 16);
        }
        __syncthreads();

        #pragma unroll
        for (int kk = 0; kk < 64; kk += 32) {
            bf16x8 af[FM], bfr[FN];
            #pragma unroll
            for (int u = 0; u < FM; ++u)
                af[u] = *(const bf16x8*)&sAt[(wy * WM + u * 16 + ln15) * 64 + kk + quad * 8];
            #pragma unroll
            for (int v = 0; v < FN; ++v)
                bfr[v] = *(const bf16x8*)&sBt[(wx * WN + v * 16 + ln15) * 64 + kk + quad * 8];
            #pragma unroll
            for (int u = 0; u < FM; ++u)
                #pragma unroll
                for (int v = 0; v < FN; ++v)
                    acc[u][v] = __builtin_amdgcn_mfma_f32_16x16x32_bf16(
                        af[u], bfr[v], acc[u][v], 0, 0, 0);
        }
        __syncthreads();
    }

    // epilogue: C/D layout col=lane&15, row=quad*4+reg
    constexpr bool OUTBF = (MODE == M_QKV || MODE == M_WEFFT || MODE == M_W2T);
    #pragma unroll
    for (int u = 0; u < FM; ++u) {
        int rg = row0 + wy * WM + u * 16 + quad * 4;
        #pragma unroll
        for (int v = 0; v < FN; ++v) {
            int cg = col0 + wx * WN + v * 16 + ln15;
            float bv = 0.f;
            if constexpr (MODE == M_QKV || MODE == M_PF) bv = biasb[cg];
            #pragma unroll
            for (int rr = 0; rr < 4; ++rr) {
                float val = acc[u][v][rr];
                if constexpr (MODE == M_SCORES) val *= scale;
                val += bv;
                if constexpr (OUTBF)
                    ((__hip_bfloat16*)Cv)[(size_t)z * strC + (size_t)(rg + rr) * ldc + cg] =
                        __float2bfloat16(val);
                else
                    ((float*)Cv)[(size_t)z * strC + (size_t)(rg + rr) * ldc + cg] = val;
            }
        }
    }
}

// ---------------------------------------------------------------------------
__global__ __launch_bounds__(256) void cvt_bf16(const float* __restrict__ in,
                                                __hip_bfloat16* __restrict__ out, int n)
{
    int i = (blockIdx.x * 256 + threadIdx.x) * 4;
    if (i >= n) return;
    float4 v = *(const float4*)(in + i);
    out[i + 0] = __float2bfloat16(v.x);
    out[i + 1] = __float2bfloat16(v.y);
    out[i + 2] = __float2bfloat16(v.z);
    out[i + 3] = __float2bfloat16(v.w);
}

// 512x512 fp32 -> transposed bf16, 3 matrices selected by blockIdx.z
__global__ __launch_bounds__(256) void transpose3(const float* __restrict__ a,
                                                  const float* __restrict__ b,
                                                  const float* __restrict__ c,
                                                  __hip_bfloat16* __restrict__ out)
{
    const float* in = (blockIdx.z == 0) ? a : (blockIdx.z == 1) ? b : c;
    __hip_bfloat16* o = out + (size_t)blockIdx.z * 512 * 512;
    __shared__ float t[32][33];
    int c0 = blockIdx.x * 32, r0 = blockIdx.y * 32;
    int tx = threadIdx.x & 31, ty = threadIdx.x >> 5;
    #pragma unroll
    for (int dy = 0; dy < 32; dy += 8)
        t[ty + dy][tx] = in[(size_t)(r0 + ty + dy) * 512 + c0 + tx];
    __syncthreads();
    #pragma unroll
    for (int dy = 0; dy < 32; dy += 8)
        o[(size_t)(c0 + ty + dy) * 512 + r0 + tx] = __float2bfloat16(t[tx][ty + dy]);
}

// out[c][r] (bf16) = in[r][c] (fp32); in is [Rr][Cc]
__global__ __launch_bounds__(256) void transpose_cvt(const float* __restrict__ in,
                                                     __hip_bfloat16* __restrict__ out,
                                                     int Rr, int Cc)
{
    __shared__ float t[32][33];
    int c0 = blockIdx.x * 32, r0 = blockIdx.y * 32;
    int tx = threadIdx.x & 31, ty = threadIdx.x >> 5;
    #pragma unroll
    for (int dy = 0; dy < 32; dy += 8)
        t[ty + dy][tx] = in[(size_t)(r0 + ty + dy) * Cc + c0 + tx];
    __syncthreads();
    #pragma unroll
    for (int dy = 0; dy < 32; dy += 8)
        out[(size_t)(c0 + ty + dy) * Rr + r0 + tx] = __float2bfloat16(t[tx][ty + dy]);
}

// bias table for fused QKV + beff init
__global__ __launch_bounds__(512) void prep_small(const float* __restrict__ bq,
                                                  const float* __restrict__ bk,
                                                  const float* __restrict__ bv,
                                                  const float* __restrict__ bo,
                                                  float* __restrict__ biasqkv,
                                                  float* __restrict__ beff)
{
    int t = threadIdx.x;
    biasqkv[t]        = bq[t];
    biasqkv[512 + t]  = bk[t];
    biasqkv[1024 + t] = bv[t];
    beff[t]           = bo[t];
}

// beff[n] += sum over this block's 128 rows of br[m]*Wo[m,n]
__global__ __launch_bounds__(512) void beff_acc(const float* __restrict__ br,
                                                const float* __restrict__ Wo,
                                                float* __restrict__ beff)
{
    int n  = threadIdx.x;
    int m0 = blockIdx.x * 128;
    float acc = 0.f;
    #pragma unroll 4
    for (int m = m0; m < m0 + 128; ++m)
        acc += br[m] * Wo[(size_t)m * D_ + n];
    atomicAdd(&beff[n], acc);
}

// ---------------------------------------------------------------------------
// One block per (b, i): restricted softmax per rate; write packed bf16 P row
// (zero-padded only out to PF's 64-block stage limit) + fp32 avg row.
// scores and avg_out alias (read first).
// ---------------------------------------------------------------------------
__global__ __launch_bounds__(256) void softmax_p(const float* __restrict__ scores,
                                                 float* __restrict__ avg_out,
                                                 __hip_bfloat16* __restrict__ P)
{
    __shared__ float s_s[S_];
    __shared__ float s_p[S_];
    __shared__ float s_avg[S_];
    __shared__ float red[4];

    int i   = blockIdx.x;
    int b   = blockIdx.y;
    int tid = threadIdx.x;
    int wv  = tid >> 6;
    int ln  = tid & 63;

    const float* srow = scores + ((size_t)b * S_ + i) * S_;
    __hip_bfloat16* prow = P + ((size_t)b * S_ + i) * KP;

    for (int j = tid; j < S_; j += 256) s_avg[j] = 0.0f;
    for (int j = tid; j <= i; j += 256) s_s[j] = srow[j];
    __syncthreads();

    const int rates[4]  = {1, 2, 4, 8};
    const int segoff[4] = {0, 2048, 3072, 3584};
    const int imax = i | 63;   // PF row-tile max (TBM=64)

    for (int ri = 0; ri < 4; ++ri) {
        int rate   = rates[ri];
        int seg    = segoff[ri];
        int segLen = S_ / rate;
        int cnt    = i / rate + 1;
        int tlim   = min(segLen, ((imax / rate) & ~63) + 64);  // PF stage extent

        float m = -INFINITY;
        for (int t = tid; t < cnt; t += 256) m = fmaxf(m, s_s[t * rate]);
        #pragma unroll
        for (int o = 32; o > 0; o >>= 1) m = fmaxf(m, __shfl_down(m, o, 64));
        if (ln == 0) red[wv] = m;
        __syncthreads();
        m = fmaxf(fmaxf(red[0], red[1]), fmaxf(red[2], red[3]));
        __syncthreads();

        float sum = 0.0f;
        for (int t = tid; t < cnt; t += 256) {
            float e = __expf(s_s[t * rate] - m);
            s_p[t] = e;
            sum += e;
        }
        #pragma unroll
        for (int o = 32; o > 0; o >>= 1) sum += __shfl_down(sum, o, 64);
        if (ln == 0) red[wv] = sum;
        __syncthreads();
        sum = red[0] + red[1] + red[2] + red[3];
        float inv = 1.0f / sum;

        for (int t = tid; t < tlim; t += 256) {
            if (t < cnt) {
                float p = s_p[t] * inv;
                s_avg[t * rate] += 0.25f * p;
                prow[seg + t] = __float2bfloat16(p);
            } else {
                prow[seg + t] = __float2bfloat16(0.0f);
            }
        }
        __syncthreads();
    }

    float* arow = avg_out + ((size_t)b * S_ + i) * S_;
    for (int j = tid; j < S_; j += 256) arow[j] = s_avg[j];
}

// ---------------------------------------------------------------------------
extern "C" void kernel_launch(void* const* d_in, const int* in_sizes, int n_in,
                              void* d_out, int out_size, void* d_ws, size_t ws_size,
                              hipStream_t stream)
{
    const float* x  = (const float*)d_in[0];
    const float* Wq = (const float*)d_in[1];
    const float* bq = (const float*)d_in[2];
    const float* Wk = (const float*)d_in[3];
    const float* bk = (const float*)d_in[4];
    const float* Wv = (const float*)d_in[5];
    const float* bv = (const float*)d_in[6];
    const float* Wr = (const float*)d_in[7];
    const float* br = (const float*)d_in[8];
    const float* Wo = (const float*)d_in[9];
    const float* bo = (const float*)d_in[10];

    float* out    = (float*)d_out;
    float* scores = out + (size_t)B_ * S_ * D_;  // avg_attention region doubles as scores

    // ---- workspace layout (bytes) ----
    char* wsb = (char*)d_ws;
    short* xb  = (short*)(wsb);                           //  4 MB  bf16 x
    short* Qb  = (short*)(wsb + (4u << 20));              //  4 MB (Q,K,V contiguous)
    short* Kb  = (short*)(wsb + (8u << 20));
    short* Vb  = (short*)(wsb + (12u << 20));
    short* P   = (short*)(wsb + (16u << 20));             // 31.5 MB (softmax_p output)
    short* W2T = (short*)(wsb + (16u << 20) + 31457280u); // 7.86 MB
    float* beff    = (float*)(wsb + (16u << 20) + 31457280u + 7864320u); // 2 KB
    float* biasqkv = beff + 512;                                          // 6 KB
    // small weight buffers live INSIDE the P region (all dead before softmax_p):
    short* WqT   = P;                                   // 3 x 512 KB contiguous
    short* Wrb   = (short*)((char*)P + 1572864);        // 2 MB
    short* WoT   = (short*)((char*)P + 3670016);        // 2 MB
    short* WeffT = (short*)((char*)P + 5767168);        // 2 MB

    const float scale = (float)(1.0 / sqrt((double)D_));

    // ---- prep: conversions / transposes / bias table / beff ----
    prep_small<<<1, 512, 0, stream>>>(bq, bk, bv, bo, biasqkv, beff);
    beff_acc<<<16, 512, 0, stream>>>(br, Wo, beff);
    cvt_bf16<<<dim3(2048), 256, 0, stream>>>(x,  (__hip_bfloat16*)xb,  B_ * S_ * D_);
    cvt_bf16<<<dim3(1024), 256, 0, stream>>>(Wr, (__hip_bfloat16*)Wrb, R_ * D_ * D_);
    transpose3<<<dim3(16, 16, 3), 256, 0, stream>>>(Wq, Wk, Wv, (__hip_bfloat16*)WqT);
    transpose_cvt<<<dim3(16, 64), 256, 0, stream>>>(Wo, (__hip_bfloat16*)WoT, 2048, 512);

    // ---- fused Q,K,V projections (bf16 out), z selects weight/bias/output ----
    mfma_nt<M_QKV, 64, 128><<<dim3(4, 64, 3), 256, 0, stream>>>(
        xb, WqT, biasqkv, Qb, 512, 512, 512, 512,
        0, 512L * 512, (long)B_ * S_ * D_, 512, 0.f);

    // ---- scores = Q K^T * scale (lower-triangle blocks only), fp32 ----
    mfma_nt<M_SCORES, 64, 128><<<dim3(16, 32, 2), 256, 0, stream>>>(
        Qb, Kb, beff, scores, 512, 512, 2048, 512,
        (long)S_ * D_, (long)S_ * D_, (long)S_ * S_, 0, scale);

    // ---- WeffT[r][n][d] = sum_m WoT[n][r*512+m] * Wr[r][d][m] (bf16) ----
    mfma_nt<M_WEFFT, 64, 64><<<dim3(8, 8, 4), 256, 0, stream>>>(
        WoT, Wrb, beff, WeffT, 2048, 512, 512, 512,
        512, (long)D_ * D_, (long)D_ * D_, 0, 0.f);

    // ---- W2T[b][n][packed j] = sum_d WeffT_r[n][d] * V[b][(j-seg)*rate][d] ----
    mfma_nt<M_W2T, 64, 128><<<dim3(30, 8, 2), 256, 0, stream>>>(
        WeffT, Vb, beff, W2T, 512, 512, 3840, 512,
        0, (long)S_ * D_, 512L * KP, 0, 0.f);

    // ---- restricted softmax -> packed bf16 P + fp32 avg (overwrites scores) ----
    softmax_p<<<dim3(S_, B_), 256, 0, stream>>>(scores, scores, (__hip_bfloat16*)P);

    // ---- out[b] = P[b] @ W2[b] + beff (k-skip, heavy rows first), fp32 ----
    mfma_nt<M_PF, 64, 64><<<dim3(8, 32, 2), 256, 0, stream>>>(
        P, W2T, beff, out, 3840, 3840, 512, 3840,
        (long)S_ * KP, 512L * KP, (long)S_ * D_, 0, 0.f);
}

// Round 5
// 207.363 us; speedup vs baseline: 9.3631x; 1.1682x over previous
//
#include <hip/hip_runtime.h>
#include <hip/hip_bf16.h>
#include <math.h>

#define B_ 2
#define S_ 2048
#define D_ 512
#define R_ 4
#define KP 3840   // packed P columns: 2048 + 1024 + 512 + 256

typedef __attribute__((ext_vector_type(8))) __bf16 bf16x8;
typedef __attribute__((ext_vector_type(4))) float f32x4;

enum { M_QKV = 0, M_SCORES = 1, M_WEFFT = 2, M_W2T = 3, M_PF = 4 };

// async global -> LDS, 16 B per lane. lds ptr must be wave-uniform base.
__device__ __forceinline__ void g2l16(const void* gp, void* lp) {
    __builtin_amdgcn_global_load_lds(
        (const __attribute__((address_space(1))) unsigned int*)(unsigned long long)gp,
        (__attribute__((address_space(3))) unsigned int*)(unsigned int)(unsigned long long)lp,
        16, 0, 0);
}

// ---------------------------------------------------------------------------
// Generic NT MFMA GEMM: C[m,n] = sum_k A[m,k] * B[n,k]  (bf16 in, fp32 acc)
// BK=128; XOR chunk swizzle (chunk c of row r stored at c^(r&7)) kills the
// 16-way LDS bank conflicts of the unswizzled layout; global_load_lds staging.
// ---------------------------------------------------------------------------
template<int MODE, int TBM, int TBN>
__global__ __launch_bounds__(256) void mfma_nt(
    const short* __restrict__ A, const short* __restrict__ B,
    const float* __restrict__ bias, void* __restrict__ Cv,
    int lda, int ldb, int ldc, int K,
    long strA, long strB, long strC, long strBias, float scale)
{
    constexpr int WM = TBM / 2, WN = TBN / 2;
    constexpr int FM = WM / 16, FN = WN / 16;

    __shared__ __bf16 sAt[TBM * 128];
    __shared__ __bf16 sBt[TBN * 128];

    const int tid  = threadIdx.x;
    const int lane = tid & 63, wid = tid >> 6;
    const int ln15 = lane & 15, quad = lane >> 4;
    const int wy = wid & 1, wx = wid >> 1;

    // heavy-first row order for PF (k-skip load imbalance)
    const int by   = (MODE == M_PF) ? (gridDim.y - 1 - blockIdx.y) : blockIdx.y;
    const int col0 = blockIdx.x * TBN;
    const int row0 = by * TBM;
    const int z    = blockIdx.z;

    if constexpr (MODE == M_SCORES) {
        if (col0 > row0 + TBM - 1) return;   // block strictly above diagonal
    }

    const short* Ab = A + (size_t)z * strA;
    const short* Bb = B + (size_t)z * strB;
    const float* biasb = bias + (size_t)z * strBias;

    int rate = 1, seg = 0;
    if constexpr (MODE == M_W2T) {
        int rIdx;
        if      (col0 >= 3584) { rate = 8; seg = 3584; rIdx = 3; }
        else if (col0 >= 3072) { rate = 4; seg = 3072; rIdx = 2; }
        else if (col0 >= 2048) { rate = 2; seg = 2048; rIdx = 1; }
        else                   { rate = 1; seg = 0;    rIdx = 0; }
        Ab += (size_t)rIdx * D_ * D_;        // WeffT for this rate
    }

    f32x4 acc[FM][FN];
    #pragma unroll
    for (int u = 0; u < FM; ++u)
        #pragma unroll
        for (int v = 0; v < FN; ++v)
            acc[u][v] = (f32x4){0.f, 0.f, 0.f, 0.f};

    for (int k0 = 0; k0 < K; k0 += 128) {
        if constexpr (MODE == M_PF) {
            int kr, ks;
            if      (k0 >= 3584) { kr = 8; ks = 3584; }
            else if (k0 >= 3072) { kr = 4; ks = 3072; }
            else if (k0 >= 2048) { kr = 2; ks = 2048; }
            else                 { kr = 1; ks = 0;    }
            if ((k0 - ks) * kr > row0 + TBM - 1) continue;  // zero k-block
        }

        // stage A tile: TBM rows x 128 cols bf16 (16 chunks of 16B per row)
        #pragma unroll
        for (int t = 0; t < TBM * 16; t += 256) {
            int idx = t + tid;
            int r = idx >> 4, clog = (idx & 15) ^ (r & 7);
            const short* g = Ab + (size_t)(row0 + r) * lda + k0 + clog * 8;
            g2l16(g, (char*)sAt + (t + wid * 64) * 16);
        }
        // stage B tile: TBN rows x 128 cols
        #pragma unroll
        for (int t = 0; t < TBN * 16; t += 256) {
            int idx = t + tid;
            int r = idx >> 4, clog = (idx & 15) ^ (r & 7);
            int grow;
            if constexpr (MODE == M_W2T) grow = (col0 + r - seg) * rate;
            else                         grow = col0 + r;
            const short* g = Bb + (size_t)grow * ldb + k0 + clog * 8;
            g2l16(g, (char*)sBt + (t + wid * 64) * 16);
        }
        __syncthreads();

        #pragma unroll
        for (int kk = 0; kk < 128; kk += 32) {
            bf16x8 af[FM], bfr[FN];
            #pragma unroll
            for (int u = 0; u < FM; ++u) {
                int ra = wy * WM + u * 16 + ln15;
                int ch = (kk >> 3) + quad;
                af[u] = *(const bf16x8*)&sAt[ra * 128 + (ch ^ (ra & 7)) * 8];
            }
            #pragma unroll
            for (int v = 0; v < FN; ++v) {
                int rb = wx * WN + v * 16 + ln15;
                int ch = (kk >> 3) + quad;
                bfr[v] = *(const bf16x8*)&sBt[rb * 128 + (ch ^ (rb & 7)) * 8];
            }
            #pragma unroll
            for (int u = 0; u < FM; ++u)
                #pragma unroll
                for (int v = 0; v < FN; ++v)
                    acc[u][v] = __builtin_amdgcn_mfma_f32_16x16x32_bf16(
                        af[u], bfr[v], acc[u][v], 0, 0, 0);
        }
        __syncthreads();
    }

    // epilogue: C/D layout col=lane&15, row=quad*4+reg
    constexpr bool OUTBF = (MODE == M_QKV || MODE == M_WEFFT || MODE == M_W2T);
    #pragma unroll
    for (int u = 0; u < FM; ++u) {
        int rg = row0 + wy * WM + u * 16 + quad * 4;
        #pragma unroll
        for (int v = 0; v < FN; ++v) {
            int cg = col0 + wx * WN + v * 16 + ln15;
            float bv = 0.f;
            if constexpr (MODE == M_QKV || MODE == M_PF) bv = biasb[cg];
            #pragma unroll
            for (int rr = 0; rr < 4; ++rr) {
                float val = acc[u][v][rr];
                if constexpr (MODE == M_SCORES) val *= scale;
                val += bv;
                if constexpr (OUTBF)
                    ((__hip_bfloat16*)Cv)[(size_t)z * strC + (size_t)(rg + rr) * ldc + cg] =
                        __float2bfloat16(val);
                else
                    ((float*)Cv)[(size_t)z * strC + (size_t)(rg + rr) * ldc + cg] = val;
            }
        }
    }
}

// ---------------------------------------------------------------------------
// fused bf16 conversions: x (2M elems) then Wr (1M elems)
__global__ __launch_bounds__(256) void prep_cvt(const float* __restrict__ x,
                                                const float* __restrict__ Wr,
                                                __hip_bfloat16* __restrict__ xb,
                                                __hip_bfloat16* __restrict__ Wrb)
{
    const size_t NX = (size_t)B_ * S_ * D_;
    size_t i = ((size_t)blockIdx.x * 256 + threadIdx.x) * 4;
    const float* in; __hip_bfloat16* out; size_t off;
    if (i < NX) { in = x; out = xb; off = i; }
    else        { in = Wr; out = Wrb; off = i - NX; }
    float4 v = *(const float4*)(in + off);
    out[off + 0] = __float2bfloat16(v.x);
    out[off + 1] = __float2bfloat16(v.y);
    out[off + 2] = __float2bfloat16(v.z);
    out[off + 3] = __float2bfloat16(v.w);
}

// fused transposes: y<48 -> Wq/Wk/Wv (512x512), else Wo (2048x512)
__global__ __launch_bounds__(256) void prep_transpose(const float* __restrict__ Wq,
                                                      const float* __restrict__ Wk,
                                                      const float* __restrict__ Wv,
                                                      const float* __restrict__ Wo,
                                                      __hip_bfloat16* __restrict__ WqT,
                                                      __hip_bfloat16* __restrict__ WoT)
{
    __shared__ float t[32][33];
    int y = blockIdx.y;
    const float* in; __hip_bfloat16* out; int Rr, r0;
    if (y < 48) {
        int w = y >> 4;
        in = (w == 0) ? Wq : (w == 1) ? Wk : Wv;
        out = WqT + (size_t)w * 512 * 512;
        Rr = 512; r0 = (y & 15) * 32;
    } else {
        in = Wo; out = WoT; Rr = 2048; r0 = (y - 48) * 32;
    }
    int c0 = blockIdx.x * 32;
    int tx = threadIdx.x & 31, ty = threadIdx.x >> 5;
    #pragma unroll
    for (int dy = 0; dy < 32; dy += 8)
        t[ty + dy][tx] = in[(size_t)(r0 + ty + dy) * 512 + c0 + tx];
    __syncthreads();
    #pragma unroll
    for (int dy = 0; dy < 32; dy += 8)
        out[(size_t)(c0 + ty + dy) * Rr + r0 + tx] = __float2bfloat16(t[tx][ty + dy]);
}

// bias table for fused QKV + beff init
__global__ __launch_bounds__(512) void prep_small(const float* __restrict__ bq,
                                                  const float* __restrict__ bk,
                                                  const float* __restrict__ bv,
                                                  const float* __restrict__ bo,
                                                  float* __restrict__ biasqkv,
                                                  float* __restrict__ beff)
{
    int t = threadIdx.x;
    biasqkv[t]        = bq[t];
    biasqkv[512 + t]  = bk[t];
    biasqkv[1024 + t] = bv[t];
    beff[t]           = bo[t];
}

// beff[n] += sum over this block's 128 rows of br[m]*Wo[m,n]
__global__ __launch_bounds__(512) void beff_acc(const float* __restrict__ br,
                                                const float* __restrict__ Wo,
                                                float* __restrict__ beff)
{
    int n  = threadIdx.x;
    int m0 = blockIdx.x * 128;
    float acc = 0.f;
    #pragma unroll 4
    for (int m = m0; m < m0 + 128; ++m)
        acc += br[m] * Wo[(size_t)m * D_ + n];
    atomicAdd(&beff[n], acc);
}

// ---------------------------------------------------------------------------
// One block per (b, i). Shared-exp trick: all rates share scores, so
// p_r[j] = e_j / S_r with e_j = exp(s_j - m1). S_r from 8 bucket sums (j%8).
// avg[j] = e_j * c[j%8]. Single exp pass, vectorized I/O.
// P zero-padded to PF's 128-granular k-skip extent.
// ---------------------------------------------------------------------------
__global__ __launch_bounds__(256) void softmax_p(const float* __restrict__ scores,
                                                 float* __restrict__ avg_out,
                                                 __hip_bfloat16* __restrict__ P)
{
    __shared__ float s_p[S_];
    __shared__ float red[4];
    __shared__ float bs[8];

    int i   = blockIdx.x;
    int b   = blockIdx.y;
    int tid = threadIdx.x;
    int wv  = tid >> 6;
    int ln  = tid & 63;

    const float* srow = scores + ((size_t)b * S_ + i) * S_;
    __bf16* prow = (__bf16*)(P + ((size_t)b * S_ + i) * KP);

    const int cnt1 = i + 1;
    const int n4   = cnt1 >> 2;

    // ---- load + global max (single max over all valid j) ----
    float m = -INFINITY;
    for (int t = tid; t < n4; t += 256) {
        float4 v = ((const float4*)srow)[t];
        ((float4*)s_p)[t] = v;
        m = fmaxf(m, fmaxf(fmaxf(v.x, v.y), fmaxf(v.z, v.w)));
    }
    for (int j = (n4 << 2) + tid; j < cnt1; j += 256) {
        float v = srow[j]; s_p[j] = v; m = fmaxf(m, v);
    }
    #pragma unroll
    for (int o = 32; o > 0; o >>= 1) m = fmaxf(m, __shfl_xor(m, o, 64));
    if (ln == 0) red[wv] = m;
    if (tid < 8) bs[tid] = 0.f;
    __syncthreads();
    m = fmaxf(fmaxf(red[0], red[1]), fmaxf(red[2], red[3]));

    // ---- exp pass + bucket sums by j%8 ----
    float a0 = 0.f, a1 = 0.f, a2 = 0.f, a3 = 0.f;  // buckets 4*(tid&1)+k
    for (int t = tid; t < n4; t += 256) {
        float4 v = ((float4*)s_p)[t];
        v.x = __expf(v.x - m); v.y = __expf(v.y - m);
        v.z = __expf(v.z - m); v.w = __expf(v.w - m);
        ((float4*)s_p)[t] = v;
        a0 += v.x; a1 += v.y; a2 += v.z; a3 += v.w;
    }
    for (int j = (n4 << 2) + tid; j < cnt1; j += 256) {
        float e = __expf(s_p[j] - m); s_p[j] = e;
        atomicAdd(&bs[j & 7], e);
    }
    // fold odd/even lane parity, then butterfly-reduce 8 buckets per wave
    float o0 = __shfl_xor(a0, 1, 64), o1 = __shfl_xor(a1, 1, 64);
    float o2 = __shfl_xor(a2, 1, 64), o3 = __shfl_xor(a3, 1, 64);
    float b8[8];
    if ((ln & 1) == 0) {
        b8[0]=a0; b8[1]=a1; b8[2]=a2; b8[3]=a3; b8[4]=o0; b8[5]=o1; b8[6]=o2; b8[7]=o3;
    } else {
        b8[0]=o0; b8[1]=o1; b8[2]=o2; b8[3]=o3; b8[4]=a0; b8[5]=a1; b8[6]=a2; b8[7]=a3;
    }
    #pragma unroll
    for (int st = 2; st < 64; st <<= 1)
        #pragma unroll
        for (int k = 0; k < 8; ++k) b8[k] += __shfl_xor(b8[k], st, 64);
    if (ln == 0) {
        #pragma unroll
        for (int k = 0; k < 8; ++k) atomicAdd(&bs[k], b8[k]);
    }
    __syncthreads();

    float S1 = bs[0]+bs[1]+bs[2]+bs[3]+bs[4]+bs[5]+bs[6]+bs[7];
    float S2 = bs[0]+bs[2]+bs[4]+bs[6];
    float S4 = bs[0]+bs[4];
    float S8 = bs[0];
    float i1 = 1.f/S1, i2 = 1.f/S2, i4 = 1.f/S4, i8 = 1.f/S8;
    float c0 = 0.25f*(i1+i2+i4+i8), c1 = 0.25f*i1, c2 = 0.25f*(i1+i2);
    float c4 = 0.25f*(i1+i2+i4);
    // c[m]: m==0->c0; odd->c1; m%4==2->c2; m==4->c4
    float cA[4] = {c0, c1, c2, c1};  // for j%8 in 0..3
    float cB[4] = {c4, c1, c2, c1};  // for j%8 in 4..7

    // ---- avg row: elementwise float4 (zeros beyond i) ----
    float* arow = avg_out + ((size_t)b * S_ + i) * S_;
    for (int t = tid; t < S_ / 4; t += 256) {
        int j = t << 2;
        float4 e = ((float4*)s_p)[t];
        const float* cc = (t & 1) ? cB : cA;
        float4 o;
        o.x = (j     < cnt1) ? e.x * cc[0] : 0.f;
        o.y = (j + 1 < cnt1) ? e.y * cc[1] : 0.f;
        o.z = (j + 2 < cnt1) ? e.z * cc[2] : 0.f;
        o.w = (j + 3 < cnt1) ? e.w * cc[3] : 0.f;
        ((float4*)arow)[t] = o;
    }

    // ---- packed P segments: p = e[t*rate] * invS_r, 16B vector stores ----
    const float invSr[4] = {i1, i2, i4, i8};
    const int   segoff[4] = {0, 2048, 3072, 3584};
    const int   imax = i | 63;   // PF row-tile max (TBM=64)
    #pragma unroll
    for (int ri = 0; ri < 4; ++ri) {
        int seg    = segoff[ri];
        int segLen = S_ >> ri;
        int cnt    = (i >> ri) + 1;
        int tlim   = min(segLen, ((imax >> ri) & ~127) + 128);  // 128-granular
        float invS = invSr[ri];
        int nch = tlim >> 3;
        for (int t8 = tid; t8 < nch; t8 += 256) {
            int t0 = t8 << 3;
            bf16x8 w;
            #pragma unroll
            for (int k = 0; k < 8; ++k) {
                int t = t0 + k;
                float p = (t < cnt) ? s_p[t << ri] * invS : 0.f;
                w[k] = (__bf16)p;
            }
            *((bf16x8*)(prow + seg) + t8) = w;
        }
    }
}

// ---------------------------------------------------------------------------
extern "C" void kernel_launch(void* const* d_in, const int* in_sizes, int n_in,
                              void* d_out, int out_size, void* d_ws, size_t ws_size,
                              hipStream_t stream)
{
    const float* x  = (const float*)d_in[0];
    const float* Wq = (const float*)d_in[1];
    const float* bq = (const float*)d_in[2];
    const float* Wk = (const float*)d_in[3];
    const float* bk = (const float*)d_in[4];
    const float* Wv = (const float*)d_in[5];
    const float* bv = (const float*)d_in[6];
    const float* Wr = (const float*)d_in[7];
    const float* br = (const float*)d_in[8];
    const float* Wo = (const float*)d_in[9];
    const float* bo = (const float*)d_in[10];

    float* out    = (float*)d_out;
    float* scores = out + (size_t)B_ * S_ * D_;  // avg_attention region doubles as scores

    // ---- workspace layout (bytes) ----
    char* wsb = (char*)d_ws;
    short* xb  = (short*)(wsb);                           //  4 MB  bf16 x
    short* Qb  = (short*)(wsb + (4u << 20));              //  4 MB (Q,K,V contiguous)
    short* Kb  = (short*)(wsb + (8u << 20));
    short* Vb  = (short*)(wsb + (12u << 20));
    short* P   = (short*)(wsb + (16u << 20));             // 31.5 MB (softmax_p output)
    short* W2T = (short*)(wsb + (16u << 20) + 31457280u); // 7.86 MB
    float* beff    = (float*)(wsb + (16u << 20) + 31457280u + 7864320u); // 2 KB
    float* biasqkv = beff + 512;                                          // 6 KB
    // small weight buffers live INSIDE the P region (all dead before softmax_p):
    short* WqT   = P;                                   // 3 x 512 KB contiguous
    short* Wrb   = (short*)((char*)P + 1572864);        // 2 MB
    short* WoT   = (short*)((char*)P + 3670016);        // 2 MB
    short* WeffT = (short*)((char*)P + 5767168);        // 2 MB

    const float scale = (float)(1.0 / sqrt((double)D_));

    // ---- prep: bias table / beff / conversions / transposes ----
    prep_small<<<1, 512, 0, stream>>>(bq, bk, bv, bo, biasqkv, beff);
    beff_acc<<<16, 512, 0, stream>>>(br, Wo, beff);
    prep_cvt<<<dim3(3072), 256, 0, stream>>>(x, Wr, (__hip_bfloat16*)xb,
                                             (__hip_bfloat16*)Wrb);
    prep_transpose<<<dim3(16, 112), 256, 0, stream>>>(
        Wq, Wk, Wv, Wo, (__hip_bfloat16*)WqT, (__hip_bfloat16*)WoT);

    // ---- fused Q,K,V projections (bf16 out), z selects weight/bias/output ----
    mfma_nt<M_QKV, 64, 128><<<dim3(4, 64, 3), 256, 0, stream>>>(
        xb, WqT, biasqkv, Qb, 512, 512, 512, 512,
        0, 512L * 512, (long)B_ * S_ * D_, 512, 0.f);

    // ---- scores = Q K^T * scale (lower-triangle blocks only), fp32 ----
    mfma_nt<M_SCORES, 64, 128><<<dim3(16, 32, 2), 256, 0, stream>>>(
        Qb, Kb, beff, scores, 512, 512, 2048, 512,
        (long)S_ * D_, (long)S_ * D_, (long)S_ * S_, 0, scale);

    // ---- WeffT[r][n][d] = sum_m WoT[n][r*512+m] * Wr[r][d][m] (bf16) ----
    mfma_nt<M_WEFFT, 64, 64><<<dim3(8, 8, 4), 256, 0, stream>>>(
        WoT, Wrb, beff, WeffT, 2048, 512, 512, 512,
        512, (long)D_ * D_, (long)D_ * D_, 0, 0.f);

    // ---- W2T[b][n][packed j] = sum_d WeffT_r[n][d] * V[b][(j-seg)*rate][d] ----
    mfma_nt<M_W2T, 64, 128><<<dim3(30, 8, 2), 256, 0, stream>>>(
        WeffT, Vb, beff, W2T, 512, 512, 3840, 512,
        0, (long)S_ * D_, 512L * KP, 0, 0.f);

    // ---- restricted softmax -> packed bf16 P + fp32 avg (overwrites scores) ----
    softmax_p<<<dim3(S_, B_), 256, 0, stream>>>(scores, scores, (__hip_bfloat16*)P);

    // ---- out[b] = P[b] @ W2[b] + beff (k-skip, heavy rows first), fp32 ----
    mfma_nt<M_PF, 64, 64><<<dim3(8, 32, 2), 256, 0, stream>>>(
        P, W2T, beff, out, 3840, 3840, 512, 3840,
        (long)S_ * KP, 512L * KP, (long)S_ * D_, 0, 0.f);
}